// Round 6
// baseline (175.197 us; speedup 1.0000x reference)
//
#include <hip/hip_runtime.h>
#include <hip/hip_cooperative_groups.h>
#include <math.h>

namespace cg = cooperative_groups;

#define BZ 32
#define SRC_LEN 2048
#define DIM 1024
#define NSPAN 64
#define NTILE (BZ * NSPAN)   // 2048 flash tiles

typedef float f4 __attribute__((ext_vector_type(4)));

__device__ __forceinline__ f4 ntload4(const float* p) {
    return __builtin_nontemporal_load((const f4*)p);
}

// One cooperative kernel, 4 phases separated by grid.sync().
// Phase math identical to R5 (which passed absmax 0.0156 vs thr 0.083).
__global__ __launch_bounds__(256, 2) void mega(
        const float* __restrict__ src, const float* __restrict__ tgt,
        const float* __restrict__ Wg, const float* __restrict__ Wo,
        const int* __restrict__ lens, float* __restrict__ out,
        float* __restrict__ proj, float* __restrict__ scores,
        float* __restrict__ part_ml, float* __restrict__ part_c,
        float* __restrict__ c_ws) {
    cg::grid_group grid = cg::this_grid();

    __shared__ float al[BZ][260];     // phases 1 & 4 activation staging (33 KB)
    __shared__ float s_c[4][1024];    // phase 2 wave-combine (16 KB)
    __shared__ float s_ml[4][2];
    __shared__ float s_m[NSPAN], s_l[NSPAN];   // phase 3

    const int t = threadIdx.x, lane = t & 63, wave = t >> 6;
    const int nblk = gridDim.x, blk0 = blockIdx.x;

    // ---------------- phase 1: proj = tgt @ Wg^T (1024 rows) ---------------
    for (int rbase = blk0 * 4; rbase < DIM; rbase += nblk * 4) {
        const int r = rbase + wave;            // wave owns one Wg row
        float acc[BZ];
#pragma unroll
        for (int b = 0; b < BZ; ++b) acc[b] = 0.f;
        for (int ks = 0; ks < 4; ++ks) {
            __syncthreads();
#pragma unroll
            for (int j = 0; j < 8; ++j) {
                const int b = wave * 8 + j;
                *(f4*)&al[b][4 * lane] = *(const f4*)&tgt[b * DIM + ks * 256 + 4 * lane];
            }
            __syncthreads();
            const f4 w = *(const f4*)&Wg[(size_t)r * DIM + ks * 256 + 4 * lane];
#pragma unroll
            for (int b = 0; b < BZ; ++b) {
                const f4 a = *(const f4*)&al[b][4 * lane];
                const f4 p = w * a;
                acc[b] += p.x + p.y + p.z + p.w;
            }
        }
#pragma unroll
        for (int b = 0; b < BZ; ++b) {
#pragma unroll
            for (int off = 32; off > 0; off >>= 1)
                acc[b] += __shfl_xor(acc[b], off, 64);
        }
        if (lane == 0) {
#pragma unroll
            for (int b = 0; b < BZ; ++b) proj[b * DIM + r] = acc[b];
        }
    }
    grid.sync();

    // ---------------- phase 2: flash over src (live rows only) -------------
    for (int tile = blk0; tile < NTILE; tile += nblk) {
        const int b = tile & 31;
        const int g = tile >> 5;
        const int len = lens[b];
        const int r0 = (g * len) >> 6;
        const int r1 = ((g + 1) * len) >> 6;   // union over g = [0, len)
        const int n = r1 - r0;
        int nb = n - 8 * wave; nb = nb < 0 ? 0 : (nb > 8 ? 8 : nb);

        f4 pj[4];
#pragma unroll
        for (int q = 0; q < 4; ++q)
            pj[q] = *(const f4*)&proj[b * DIM + (q * 64 + lane) * 4];

        const float* sb = src + ((size_t)b * SRC_LEN + r0 + 8 * wave) * DIM;

        f4 v[8][4];
#pragma unroll
        for (int r = 0; r < 8; ++r) {
            if (r < nb) {
#pragma unroll
                for (int q = 0; q < 4; ++q)
                    v[r][q] = ntload4(&sb[r * DIM + (q * 64 + lane) * 4]);
            }
        }
        float sc[8];
#pragma unroll
        for (int r = 0; r < 8; ++r) {
            if (r < nb) {
                const f4 d = v[r][0] * pj[0] + v[r][1] * pj[1] +
                             v[r][2] * pj[2] + v[r][3] * pj[3];
                sc[r] = d.x + d.y + d.z + d.w;
            } else {
                sc[r] = -INFINITY;
            }
        }
#pragma unroll
        for (int off = 32; off > 0; off >>= 1) {
#pragma unroll
            for (int r = 0; r < 8; ++r) sc[r] += __shfl_xor(sc[r], off, 64);
        }
        if (lane == 0) {
#pragma unroll
            for (int r = 0; r < 8; ++r)
                if (r < nb) scores[b * SRC_LEN + r0 + 8 * wave + r] = sc[r];
        }

        float m = -INFINITY, l = 0.f;
        f4 c[4] = {{0.f,0.f,0.f,0.f},{0.f,0.f,0.f,0.f},{0.f,0.f,0.f,0.f},{0.f,0.f,0.f,0.f}};
        if (nb > 0) {
#pragma unroll
            for (int r = 0; r < 8; ++r) m = fmaxf(m, sc[r]);
            float w[8];
#pragma unroll
            for (int r = 0; r < 8; ++r) { w[r] = __expf(sc[r] - m); l += w[r]; }
#pragma unroll
            for (int r = 0; r < 8; ++r) {
                if (r < nb) {
#pragma unroll
                    for (int q = 0; q < 4; ++q) c[q] += w[r] * v[r][q];
                }
            }
        }

        __syncthreads();   // protect s_c against previous tile-iteration reads
#pragma unroll
        for (int q = 0; q < 4; ++q)
            *(f4*)&s_c[wave][(q * 64 + lane) * 4] = c[q];
        if (lane == 0) { s_ml[wave][0] = m; s_ml[wave][1] = l; }
        __syncthreads();

        float M = fmaxf(fmaxf(s_ml[0][0], s_ml[1][0]), fmaxf(s_ml[2][0], s_ml[3][0]));
        float L = 0.f;
        f4 acc = {0.f, 0.f, 0.f, 0.f};
#pragma unroll
        for (int wv = 0; wv < 4; ++wv) {
            const float mw = s_ml[wv][0];
            const float e = (mw == -INFINITY) ? 0.f : __expf(mw - M);
            L += e * s_ml[wv][1];
            const f4 cv = *(const f4*)&s_c[wv][t * 4];
            acc += e * cv;
        }
        if (t == 0) { part_ml[2 * tile] = M; part_ml[2 * tile + 1] = L; }
        if (M > -INFINITY)
            *(f4*)&part_c[(size_t)tile * DIM + t * 4] = acc;
    }
    grid.sync();

    // ---------------- phase 3: merge partials -> c_ws, align ---------------
    for (int vb = blk0; vb < 128; vb += nblk) {
        const int b = vb & 31;
        const int slice = vb >> 5;
        __syncthreads();
        if (t < NSPAN) {
            s_m[t] = part_ml[2 * (t * BZ + b)];
            s_l[t] = part_ml[2 * (t * BZ + b) + 1];
        }
        __syncthreads();
        float M = -INFINITY;
#pragma unroll
        for (int i = 0; i < NSPAN; ++i) M = fmaxf(M, s_m[i]);
        float L = 0.f;
#pragma unroll
        for (int i = 0; i < NSPAN; ++i)
            if (s_m[i] > -INFINITY) L += __expf(s_m[i] - M) * s_l[i];
        const float invL = 1.f / L;

        const int col = slice * 256 + t;
        float acc = 0.f;
        for (int i = 0; i < NSPAN; ++i) {
            if (s_m[i] > -INFINITY)
                acc += __expf(s_m[i] - M) * part_c[(size_t)(i * BZ + b) * DIM + col];
        }
        c_ws[b * DIM + col] = acc * invL;

        const int len = lens[b];
#pragma unroll
        for (int u = 0; u < 2; ++u) {
            const int s = slice * 512 + u * 256 + t;
            float a = 0.f;
            if (s < len) a = __expf(scores[b * SRC_LEN + s] - M) * invL;
            out[BZ * DIM + b * SRC_LEN + s] = a;     // align chunk of d_out
        }
    }
    grid.sync();

    // ---------------- phase 4: attn_h = [c, tgt] @ Wo^T (1024 rows) --------
    for (int rbase = blk0 * 4; rbase < DIM; rbase += nblk * 4) {
        const int r = rbase + wave;
        float acc[BZ];
#pragma unroll
        for (int b = 0; b < BZ; ++b) acc[b] = 0.f;
        for (int ks = 0; ks < 8; ++ks) {
            __syncthreads();
            const float* actsrc = (ks < 4) ? &c_ws[ks * 256] : &tgt[(ks - 4) * 256];
#pragma unroll
            for (int j = 0; j < 8; ++j) {
                const int b = wave * 8 + j;
                *(f4*)&al[b][4 * lane] = *(const f4*)&actsrc[b * DIM + 4 * lane];
            }
            __syncthreads();
            const f4 w = *(const f4*)&Wo[(size_t)r * (2 * DIM) + ks * 256 + 4 * lane];
#pragma unroll
            for (int b = 0; b < BZ; ++b) {
                const f4 a = *(const f4*)&al[b][4 * lane];
                const f4 p = w * a;
                acc[b] += p.x + p.y + p.z + p.w;
            }
        }
#pragma unroll
        for (int b = 0; b < BZ; ++b) {
#pragma unroll
            for (int off = 32; off > 0; off >>= 1)
                acc[b] += __shfl_xor(acc[b], off, 64);
        }
        if (lane == 0) {
#pragma unroll
            for (int b = 0; b < BZ; ++b) out[b * DIM + r] = acc[b];
        }
    }
}

extern "C" void kernel_launch(void* const* d_in, const int* in_sizes, int n_in,
                              void* d_out, int out_size, void* d_ws, size_t ws_size,
                              hipStream_t stream) {
    const float* src = (const float*)d_in[0];   // (32, 2048, 1024)
    const float* tgt = (const float*)d_in[1];   // (32, 1, 1024)
    const float* Wg  = (const float*)d_in[2];   // (1024, 1024)
    const float* Wo  = (const float*)d_in[3];   // (1024, 2048)
    const int*   len = (const int*)d_in[4];     // (32,)
    float* out = (float*)d_out;                 // attn_h [0,32768) ++ align

    float* ws = (float*)d_ws;
    float* proj    = ws;                               // 32*1024
    float* scores  = proj + BZ * DIM;                  // 32*2048
    float* part_ml = scores + BZ * SRC_LEN;            // 2048*2
    float* part_c  = part_ml + NTILE * 2;              // 2048*1024 (8 MB)
    float* c_ws    = part_c + (size_t)NTILE * DIM;     // 32*1024

    // grid sized to guaranteed co-residency (occupancy query; 256 CUs on MI355X)
    int perCU = 0;
    (void)hipOccupancyMaxActiveBlocksPerMultiprocessor(&perCU,
            reinterpret_cast<const void*>(mega), 256, 0);
    int nblk = perCU * 256;
    if (nblk > 512) nblk = 512;
    if (nblk < 1) nblk = 256;   // paranoia fallback

    void* args[] = { (void*)&src, (void*)&tgt, (void*)&Wg, (void*)&Wo,
                     (void*)&len, (void*)&out, (void*)&proj, (void*)&scores,
                     (void*)&part_ml, (void*)&part_c, (void*)&c_ws };
    (void)hipLaunchCooperativeKernel(reinterpret_cast<const void*>(mega),
                                     dim3(nblk), dim3(256), args, 0, stream);
}